// Round 22
// baseline (224.085 us; speedup 1.0000x reference)
//
#include <hip/hip_runtime.h>
#include <stdint.h>

typedef unsigned short u16;
typedef __attribute__((ext_vector_type(8))) short bf16x8;
typedef __attribute__((ext_vector_type(4))) float f32x4;

#define S_LEN 4096
#define HID_DIM 2304
#define QKV_N 4096
#define AO_N 2048
#define HD 256
#define WIN 1024
#define QSCALE 0.0625f

static __device__ __forceinline__ u16 f2bf(float f) {
  union { float f; uint32_t u; } v; v.f = f;
  return (u16)((v.u + 0x7FFFu + ((v.u >> 16) & 1u)) >> 16);
}
static __device__ __forceinline__ float bf2f(u16 h) {
  union { uint32_t u; float f; } v; v.u = ((uint32_t)h) << 16;
  return v.f;
}

static __device__ __forceinline__ void gld16(const void* src, void* dst) {
  __builtin_amdgcn_global_load_lds((const __attribute__((address_space(1))) void*)src,
                                   (__attribute__((address_space(3))) void*)dst, 16, 0, 0);
}

#define BAR() __builtin_amdgcn_s_barrier()
#define LG0() asm volatile("s_waitcnt lgkmcnt(0)" ::: "memory")
#define VM6() asm volatile("s_waitcnt vmcnt(6)" ::: "memory")
#define VM5() asm volatile("s_waitcnt vmcnt(5)" ::: "memory")
#define VM4() asm volatile("s_waitcnt vmcnt(4)" ::: "memory")
#define VM3() asm volatile("s_waitcnt vmcnt(3)" ::: "memory")
#define VM2() asm volatile("s_waitcnt vmcnt(2)" ::: "memory")
#define VM0() asm volatile("s_waitcnt vmcnt(0)" ::: "memory")
#define PRIO1() __builtin_amdgcn_s_setprio(1)
#define PRIO0() __builtin_amdgcn_s_setprio(0)

// ---------------- fused prep: x->bf16 | RoPE tables | wq/wk/wv transpose ----------------
// blocks [0,9216): cvt x; [9216,11264): sincos; [11264,20480): transpose_w.
__global__ __launch_bounds__(256) void k_prep(const float* __restrict__ x,
                                              u16* __restrict__ xbf,
                                              const int* __restrict__ pos_ids,
                                              float* __restrict__ ctab,
                                              float* __restrict__ stab,
                                              const float* __restrict__ wq,
                                              const float* __restrict__ wk,
                                              const float* __restrict__ wv,
                                              u16* __restrict__ wT) {
  __shared__ float tile[32][33];
  const int b = blockIdx.x;
  if (b < 9216) {
    int i = (b * 256 + threadIdx.x) * 4;
    float4 v = *(const float4*)(x + i);
    uint64_t p = (uint64_t)f2bf(v.x) | ((uint64_t)f2bf(v.y) << 16)
               | ((uint64_t)f2bf(v.z) << 32) | ((uint64_t)f2bf(v.w) << 48);
    *(uint64_t*)(xbf + i) = p;
  } else if (b < 11264) {
    int idx = (b - 9216) * 256 + threadIdx.x;  // 4096*128
    int s = idx >> 7, j = idx & 127;
    float ang = (float)pos_ids[s] * exp2f((float)j * (-13.287712379549449f / 128.0f));
    float sn, c;
    sincosf(ang, &sn, &c);
    ctab[idx] = c;
    stab[idx] = sn;
  } else {
    int bb = b - 11264;           // 0..9215
    int ct = bb & 127;            // 0..127 -> out rows ct*32..+31
    int r0 = (bb >> 7) * 32;      // over 2304
    const float* src;
    int C, c0;
    if (ct < 64) {
      src = wq; C = 2048; c0 = ct * 32;
    } else if (ct < 96) {
      src = wk; C = 1024; c0 = (ct - 64) * 32;
    } else {
      src = wv; C = 1024; c0 = (ct - 96) * 32;
    }
    int tx = threadIdx.x & 31, ty = threadIdx.x >> 5;
#pragma unroll
    for (int i = 0; i < 4; i++)
      tile[ty + i * 8][tx] = src[(size_t)(r0 + ty + i * 8) * C + c0 + tx];
    __syncthreads();
#pragma unroll
    for (int i = 0; i < 4; i++)
      wT[(size_t)(ct * 32 + ty + i * 8) * HID_DIM + r0 + tx] = f2bf(tile[tx][ty + i * 8]);
  }
}

// ---------------- bf16 GEMM: 256x256, BK=64, 4-phase, uniform lag-4 staging -------------
// (R16-proven.) MODE 1 fused epilogue (2-m slab rounds; coalesced V stores). 2D XCD rect.
template <int MODE>
__global__ __launch_bounds__(512, 2) void k_gemm8p(const u16* __restrict__ A,
                                                   const u16* __restrict__ Bt,
                                                   void* __restrict__ Cout,
                                                   int M, int N, int K,
                                                   const float* __restrict__ ctab,
                                                   const float* __restrict__ stab,
                                                   const float* __restrict__ qnw,
                                                   const float* __restrict__ knw,
                                                   u16* __restrict__ vtb) {
  __shared__ u16 sAB[4 * 256 * 64];  // sA0, sA1, sB0, sB1 (contiguous)
  const int t = threadIdx.x, lane = t & 63, wave = t >> 6;
  const int wr = wave >> 2, wc = wave & 3;
  const int l15 = lane & 15, l4 = lane >> 4;
  const int nbn = N >> 8;
  int bm, bn;
  {
    const int xcd = (int)blockIdx.x & 7, loc = (int)blockIdx.x >> 3;
    if (nbn == 16) {  // grid 256: 4bm x 8bn rect per XCD
      bm = (xcd >> 1) * 4 + (loc >> 3);
      bn = (xcd & 1) * 8 + (loc & 7);
    } else {
      const int cpx = gridDim.x >> 3;
      const int wg = xcd * cpx + loc;
      bm = wg / nbn;
      bn = wg % nbn;
    }
  }
  const int NT = K >> 6;
  const int srow = lane >> 3;
  const int sslot = ((lane & 7) ^ srow) * 8;
  const u16* Abase = A + (size_t)(bm * 256) * K;
  const u16* Bbase = Bt + (size_t)(bn * 256) * K;
  f32x4 acc[8][4] = {};
  bf16x8 aF[4][2], b01[2][2], b23[2][2];

#define SA_(b) (&sAB[(b) * 16384])
#define SB_(b) (&sAB[32768 + (b) * 16384])
#define STG_A(BUF, HALF, KT) do {                                                 \
    _Pragma("unroll")                                                             \
    for (int c_ = 0; c_ < 2; c_++) {                                              \
      int rb_ = (HALF) * 128 + (wave * 2 + c_) * 8;                               \
      gld16(Abase + (size_t)(rb_ + srow) * K + ((KT) << 6) + sslot,               \
            SA_(BUF) + rb_ * 64);                                                 \
    }                                                                             \
  } while (0)
#define STG_B(BUF, HALF, KT) do {                                                 \
    _Pragma("unroll")                                                             \
    for (int c_ = 0; c_ < 2; c_++) {                                              \
      int rb_ = (HALF) * 128 + (wave * 2 + c_) * 8;                               \
      gld16(Bbase + (size_t)(rb_ + srow) * K + ((KT) << 6) + sslot,               \
            SB_(BUF) + rb_ * 64);                                                 \
    }                                                                             \
  } while (0)
#define LDA(BUF, M_, KK)                                                          \
  (*(const bf16x8*)&SA_(BUF)[((M_) * 32 + wr * 16 + l15) * 64 +                   \
                             ((((KK) << 2) + l4) ^ (l15 & 7)) * 8])
#define LDB(BUF, N_, KK)                                                          \
  (*(const bf16x8*)&SB_(BUF)[((N_) * 64 + wc * 16 + l15) * 64 +                   \
                             ((((KK) << 2) + l4) ^ (l15 & 7)) * 8])

#define P1_LOADS(b_) do {                                                         \
    _Pragma("unroll") for (int m_ = 0; m_ < 4; m_++)                              \
      _Pragma("unroll") for (int k_ = 0; k_ < 2; k_++)                            \
        aF[m_][k_] = LDA(b_, m_, k_);                                             \
    _Pragma("unroll") for (int n_ = 0; n_ < 2; n_++)                              \
      _Pragma("unroll") for (int k_ = 0; k_ < 2; k_++)                            \
        b01[n_][k_] = LDB(b_, n_, k_);                                            \
  } while (0)
#define P2_LOADS(b_) do {                                                         \
    _Pragma("unroll") for (int n_ = 0; n_ < 2; n_++)                              \
      _Pragma("unroll") for (int k_ = 0; k_ < 2; k_++)                            \
        b23[n_][k_] = LDB(b_, n_ + 2, k_);                                        \
  } while (0)
#define P3_LOADS(b_) do {                                                         \
    _Pragma("unroll") for (int m_ = 0; m_ < 4; m_++)                              \
      _Pragma("unroll") for (int k_ = 0; k_ < 2; k_++)                            \
        aF[m_][k_] = LDA(b_, m_ + 4, k_);                                         \
  } while (0)
#define MFMA16(MOFF, NOFF, BREG) do {                                             \
    _Pragma("unroll") for (int m_ = 0; m_ < 4; m_++)                              \
      _Pragma("unroll") for (int n_ = 0; n_ < 2; n_++)                            \
        _Pragma("unroll") for (int k_ = 0; k_ < 2; k_++)                          \
          acc[m_ + MOFF][n_ + NOFF] = __builtin_amdgcn_mfma_f32_16x16x32_bf16(    \
              aF[m_][k_], BREG[n_][k_], acc[m_ + MOFF][n_ + NOFF], 0, 0, 0);      \
  } while (0)

  STG_A(0, 0, 0);
  STG_B(0, 0, 0);
  STG_B(0, 1, 0);
  STG_A(0, 1, 0);
  VM4();
  BAR();

  for (int tt = 0; tt < NT - 1; ++tt) {
    const int b = tt & 1, nb = b ^ 1;
    P1_LOADS(b);
    STG_A(nb, 0, tt + 1);
    STG_B(nb, 0, tt + 1);
    BAR(); LG0(); PRIO1(); MFMA16(0, 0, b01); PRIO0();
    VM6();
    BAR();
    P2_LOADS(b);
    STG_B(nb, 1, tt + 1);
    BAR(); LG0(); PRIO1(); MFMA16(0, 2, b23); PRIO0();
    VM6();
    BAR();
    P3_LOADS(b);
    STG_A(nb, 1, tt + 1);
    BAR(); LG0(); PRIO1(); MFMA16(4, 0, b01); PRIO0();
    BAR();
    PRIO1(); MFMA16(4, 2, b23); PRIO0();
    VM4();
    BAR();
  }
  {
    const int b = (NT - 1) & 1;
    P1_LOADS(b);
    BAR(); LG0(); PRIO1(); MFMA16(0, 0, b01); PRIO0();
    VM2();
    BAR();
    P2_LOADS(b);
    BAR(); LG0(); PRIO1(); MFMA16(0, 2, b23); PRIO0();
    VM0();
    BAR();
    P3_LOADS(b);
    BAR(); LG0(); PRIO1(); MFMA16(4, 0, b01); PRIO0();
    BAR();
    PRIO1(); MFMA16(4, 2, b23); PRIO0();
  }

  if (MODE == 1) {
    __syncthreads();
    float* slab = (float*)sAB;  // [64][264] f32 (2 m-chunks per round)
    if (bn < 12) {
      const float* wvec = (bn < 8) ? qnw : knw;
      const float scl = (bn < 8) ? QSCALE : 1.0f;
      f32x4 wv4 = *(const f32x4*)&wvec[lane * 4];
#pragma unroll
      for (int mp = 0; mp < 4; mp++) {
#pragma unroll
        for (int mh = 0; mh < 2; mh++) {
          int m = mp * 2 + mh;
#pragma unroll
          for (int n = 0; n < 4; n++)
#pragma unroll
            for (int r = 0; r < 4; r++)
              slab[(mh * 32 + wr * 16 + l4 * 4 + r) * 264 + n * 64 + wc * 16 + l15] =
                  acc[m][n][r];
        }
        __syncthreads();
#pragma unroll
        for (int rr = 0; rr < 8; rr++) {
          int lrow = wave * 8 + rr;
          int grow = bm * 256 + mp * 64 + lrow;
          f32x4 v = *(const f32x4*)&slab[lrow * 264 + lane * 4];
          float ss = v[0] * v[0] + v[1] * v[1] + v[2] * v[2] + v[3] * v[3];
#pragma unroll
          for (int off = 1; off < 64; off <<= 1) ss += __shfl_xor(ss, off);
          float rms = rsqrtf(ss * (1.0f / 256.0f) + 1e-6f);
          float y[4], yo[4];
#pragma unroll
          for (int j = 0; j < 4; j++) y[j] = v[j] * rms * (1.0f + wv4[j]);
#pragma unroll
          for (int j = 0; j < 4; j++) yo[j] = __shfl_xor(y[j], 32);
          f32x4 cv = *(const f32x4*)&ctab[grow * 128 + (lane & 31) * 4];
          f32x4 sv = *(const f32x4*)&stab[grow * 128 + (lane & 31) * 4];
          uint64_t pk = 0;
#pragma unroll
          for (int j = 0; j < 4; j++) {
            float o = (lane < 32) ? (y[j] * cv[j] - yo[j] * sv[j])
                                  : (yo[j] * sv[j] + y[j] * cv[j]);
            pk |= (uint64_t)f2bf(o * scl) << (16 * j);
          }
          *(uint64_t*)&((u16*)Cout)[(size_t)grow * N + bn * 256 + lane * 4] = pk;
        }
        __syncthreads();
      }
    } else {
      const int kvh = bn - 12;
      const int dcol = wave * 32 + (lane >> 1);  // 0..255
      const int shalf = (lane & 1) * 32;
#pragma unroll
      for (int mp = 0; mp < 4; mp++) {
#pragma unroll
        for (int mh = 0; mh < 2; mh++) {
          int m = mp * 2 + mh;
#pragma unroll
          for (int n = 0; n < 4; n++)
#pragma unroll
            for (int r = 0; r < 4; r++)
              slab[(mh * 32 + wr * 16 + l4 * 4 + r) * 264 + n * 64 + wc * 16 + l15] =
                  acc[m][n][r];
        }
        __syncthreads();
        u16* dst = vtb + (size_t)(kvh * 256 + dcol) * S_LEN + bm * 256 + mp * 64 + shalf;
#pragma unroll
        for (int g = 0; g < 4; g++) {
          u16 tmp[8];
#pragma unroll
          for (int jj = 0; jj < 8; jj++)
            tmp[jj] = f2bf(slab[(shalf + g * 8 + jj) * 264 + dcol]);
          *(bf16x8*)(dst + g * 8) = *(const bf16x8*)tmp;
        }
        __syncthreads();
      }
    }
  } else {
#pragma unroll
    for (int m = 0; m < 8; m++)
#pragma unroll
      for (int n = 0; n < 4; n++)
#pragma unroll
        for (int r = 0; r < 4; r++) {
          size_t row = bm * 256 + m * 32 + wr * 16 + l4 * 4 + r;
          size_t col = bn * 256 + n * 64 + wc * 16 + l15;
          ((float*)Cout)[row * N + col] = acc[m][n][r];
        }
  }
#undef SA_
#undef SB_
#undef STG_A
#undef STG_B
#undef LDA
#undef LDB
#undef P1_LOADS
#undef P2_LOADS
#undef P3_LOADS
#undef MFMA16
}

// ---------------- bf16 GEMM 256x192 (out-proj): 4-phase, uniform lag-4 staging ----------
__global__ __launch_bounds__(512, 2) void k_gemm192(const u16* __restrict__ A,
                                                    const u16* __restrict__ Bt,
                                                    float* __restrict__ Cout,
                                                    int M, int N, int K) {
  __shared__ u16 sA[2][256 * 64];
  __shared__ u16 sB[2][192 * 64];
  const int t = threadIdx.x, lane = t & 63, wave = t >> 6;
  const int wr = wave >> 2, wc = wave & 3;
  const int l15 = lane & 15, l4 = lane >> 4;
  const int xcd = (int)blockIdx.x & 7, loc = (int)blockIdx.x >> 3;  // loc 0..23
  const int bm = (xcd >> 1) * 4 + loc / 6;
  const int bn = (xcd & 1) * 6 + loc % 6;
  const int NT = K >> 6;
  const int srow = lane >> 3;
  const int sslot = ((lane & 7) ^ srow) * 8;
  const u16* Abase = A + (size_t)(bm * 256) * K;
  const u16* Bbase = Bt + (size_t)(bn * 192) * K;
  f32x4 acc[8][3] = {};
  bf16x8 aF[4][2], b01[2][2], b2[2];

#define GA_STG_A(BUF, HALF, KT) do {                                              \
    _Pragma("unroll")                                                             \
    for (int c_ = 0; c_ < 2; c_++) {                                              \
      int rb_ = (HALF) * 128 + (wave * 2 + c_) * 8;                               \
      gld16(Abase + (size_t)(rb_ + srow) * K + ((KT) << 6) + sslot,               \
            &sA[BUF][rb_ * 64]);                                                  \
    }                                                                             \
  } while (0)
#define GA_STG_BC(BUF, CH, KT) do {                                               \
    int rb_ = (CH) * 64 + wave * 8;                                               \
    gld16(Bbase + (size_t)(rb_ + srow) * K + ((KT) << 6) + sslot,                 \
          &sB[BUF][rb_ * 64]);                                                    \
  } while (0)
#define GA_LDA(BUF, M_, KK)                                                       \
  (*(const bf16x8*)&sA[BUF][((M_) * 32 + wr * 16 + l15) * 64 +                    \
                            ((((KK) << 2) + l4) ^ (l15 & 7)) * 8])
#define GA_LDB(BUF, N_, KK)                                                       \
  (*(const bf16x8*)&sB[BUF][((N_) * 64 + wc * 16 + l15) * 64 +                    \
                            ((((KK) << 2) + l4) ^ (l15 & 7)) * 8])
#define GA_P1_LOADS(b_) do {                                                      \
    _Pragma("unroll") for (int m_ = 0; m_ < 4; m_++)                              \
      _Pragma("unroll") for (int k_ = 0; k_ < 2; k_++)                            \
        aF[m_][k_] = GA_LDA(b_, m_, k_);                                          \
    _Pragma("unroll") for (int n_ = 0; n_ < 2; n_++)                              \
      _Pragma("unroll") for (int k_ = 0; k_ < 2; k_++)                            \
        b01[n_][k_] = GA_LDB(b_, n_, k_);                                         \
  } while (0)
#define GA_P2_LOADS(b_) do {                                                      \
    _Pragma("unroll") for (int k_ = 0; k_ < 2; k_++)                              \
      b2[k_] = GA_LDB(b_, 2, k_);                                                 \
  } while (0)
#define GA_P3_LOADS(b_) do {                                                      \
    _Pragma("unroll") for (int m_ = 0; m_ < 4; m_++)                              \
      _Pragma("unroll") for (int k_ = 0; k_ < 2; k_++)                            \
        aF[m_][k_] = GA_LDA(b_, m_ + 4, k_);                                      \
  } while (0)
#define GA_MFMA_N01(MOFF) do {                                                    \
    _Pragma("unroll") for (int m_ = 0; m_ < 4; m_++)                              \
      _Pragma("unroll") for (int n_ = 0; n_ < 2; n_++)                            \
        _Pragma("unroll") for (int k_ = 0; k_ < 2; k_++)                          \
          acc[m_ + MOFF][n_] = __builtin_amdgcn_mfma_f32_16x16x32_bf16(           \
              aF[m_][k_], b01[n_][k_], acc[m_ + MOFF][n_], 0, 0, 0);              \
  } while (0)
#define GA_MFMA_N2(MOFF) do {                                                     \
    _Pragma("unroll") for (int m_ = 0; m_ < 4; m_++)                              \
      _Pragma("unroll") for (int k_ = 0; k_ < 2; k_++)                            \
        acc[m_ + MOFF][2] = __builtin_amdgcn_mfma_f32_16x16x32_bf16(              \
            aF[m_][k_], b2[k_], acc[m_ + MOFF][2], 0, 0, 0);                      \
  } while (0)

  GA_STG_A(0, 0, 0);
  GA_STG_BC(0, 0, 0);
  GA_STG_BC(0, 1, 0);
  GA_STG_BC(0, 2, 0);
  GA_STG_A(0, 1, 0);
  VM3();
  BAR();

  for (int tt = 0; tt < NT - 1; ++tt) {
    const int b = tt & 1, nb = b ^ 1;
    GA_P1_LOADS(b);
    GA_STG_A(nb, 0, tt + 1);
    GA_STG_BC(nb, 0, tt + 1);
    GA_STG_BC(nb, 1, tt + 1);
    BAR(); LG0(); PRIO1(); GA_MFMA_N01(0); PRIO0();
    VM6();
    BAR();
    GA_P2_LOADS(b);
    GA_STG_BC(nb, 2, tt + 1);
    BAR(); LG0(); PRIO1(); GA_MFMA_N2(0); PRIO0();
    VM5();
    BAR();
    GA_P3_LOADS(b);
    GA_STG_A(nb, 1, tt + 1);
    BAR(); LG0(); PRIO1(); GA_MFMA_N01(4); PRIO0();
    BAR();
    PRIO1(); GA_MFMA_N2(4); PRIO0();
    VM3();
    BAR();
  }
  {
    const int b = (NT - 1) & 1;
    GA_P1_LOADS(b);
    BAR(); LG0(); PRIO1(); GA_MFMA_N01(0); PRIO0();
    VM2();
    BAR();
    GA_P2_LOADS(b);
    BAR(); LG0(); PRIO1(); GA_MFMA_N2(0); PRIO0();
    VM0();
    BAR();
    GA_P3_LOADS(b);
    BAR(); LG0(); PRIO1(); GA_MFMA_N01(4); PRIO0();
    BAR();
    PRIO1(); GA_MFMA_N2(4); PRIO0();
  }

#pragma unroll
  for (int m = 0; m < 8; m++)
#pragma unroll
    for (int n = 0; n < 3; n++)
#pragma unroll
      for (int r = 0; r < 4; r++) {
        size_t row = bm * 256 + m * 32 + wr * 16 + l4 * 4 + r;
        size_t col = bn * 192 + n * 64 + wc * 16 + l15;
        Cout[row * N + col] = acc[m][n][r];
      }
#undef GA_STG_A
#undef GA_STG_BC
#undef GA_LDA
#undef GA_LDB
#undef GA_P1_LOADS
#undef GA_P2_LOADS
#undef GA_P3_LOADS
#undef GA_MFMA_N01
#undef GA_MFMA_N2
}

// ---------------- flash attention v10 + fused wo-transpose tail -------------------------
// blocks [0,256): attention (swapped-QK in-reg softmax, R20-proven).
// blocks [256,4864): wo [2048][2304] f32 -> wT [2304][2048] bf16, 32x32 tiles (512 thr).
// wT's prior content (wqkv^T) was consumed by gemm<1>; gemm192 consumes wo^T after.
__global__ __launch_bounds__(512, 2) void k_attn(const u16* __restrict__ qkv,
                                                 const u16* __restrict__ vt,
                                                 const int* __restrict__ pos_ids,
                                                 u16* __restrict__ aout,
                                                 const float* __restrict__ wo,
                                                 u16* __restrict__ wT) {
  __shared__ u16 lK[2][64 * 256];  // [key][d], rows 512B, swizzled
  __shared__ u16 lV[2][256 * 64];  // [d][key], rows 128B, swizzled
  const int bid = blockIdx.x;
  if (bid >= 256) {
    // ---- wo transpose tile: bb in [0,4608), cols c0 over 2304, rows r0 over 2048 ----
    const int bb = bid - 256;
    const int c0 = (bb % 72) * 32;
    const int r0 = (bb / 72) * 32;
    float* tile = (float*)&lK[0][0];  // [32][33] f32, aliased into lK
    const int tx = threadIdx.x & 31, ty = threadIdx.x >> 5;  // ty 0..15
#pragma unroll
    for (int i = 0; i < 2; i++)
      tile[(ty + i * 16) * 33 + tx] = wo[(size_t)(r0 + ty + i * 16) * HID_DIM + c0 + tx];
    __syncthreads();
#pragma unroll
    for (int i = 0; i < 2; i++)
      wT[(size_t)(c0 + ty + i * 16) * 2048 + r0 + tx] = f2bf(tile[tx * 33 + ty + i * 16]);
    return;
  }
  const int wg = (bid & 7) * 32 + (bid >> 3);  // bijective XCD swizzle
  const int kvh = wg >> 6;                     // 0..3
  const int q0 = (wg & 63) * 64;               // 0..4032
  const int t = threadIdx.x, lane = t & 63, wave = t >> 6;
  const int l15 = lane & 15, l4 = lane >> 4;
  const int head = kvh * 2 + (wave >> 2);
  const int qw = q0 + (wave & 3) * 16;

  bf16x8 qfr[8];
  {
    const u16* qptr = qkv + (size_t)(qw + l15) * QKV_N + head * HD + l4 * 8;
#pragma unroll
    for (int kc = 0; kc < 8; kc++) qfr[kc] = *(const bf16x8*)(qptr + kc * 32);
  }
  f32x4 acc[16] = {};
  float mreg = -1e30f, lreg = 0.0f;        // per-lane, query q = qw + l15
  const int qpos = qw + l15;               // pos_ids is arange (per problem setup)

  const int krw = lane >> 5, kcl = lane & 31;
  const int vrw = lane >> 3, vcl = lane & 7;
  const u16* kgb = qkv + 2048 + kvh * HD;
  const u16* vgb = vt + (size_t)kvh * HD * S_LEN;

  int start = q0 - (WIN - 1);
  if (start < 0) start = 0;
  start &= ~63;

#define STAGE_KV(B, T0) do {                                                          \
    _Pragma("unroll")                                                                 \
    for (int i_ = 0; i_ < 4; i_++) {                                                  \
      int ch_ = wave * 4 + i_;                                                        \
      int kr_ = ch_ * 2 + krw;                                                        \
      gld16(kgb + (size_t)((T0) + kr_) * QKV_N + ((kcl ^ (kr_ & 7)) * 8),             \
            &lK[B][ch_ * 512]);                                                       \
      int vr_ = ch_ * 8 + vrw;                                                        \
      gld16(vgb + (size_t)vr_ * S_LEN + (T0) + ((vcl ^ (vr_ & 7)) * 8),               \
            &lV[B][ch_ * 512]);                                                       \
    }                                                                                 \
  } while (0)

  STAGE_KV(0, start);
  __syncthreads();
  int buf = 0;
  for (int t0 = start; t0 <= q0 + 63; t0 += 64) {
    if (t0 + 64 <= q0 + 63) STAGE_KV(buf ^ 1, t0 + 64);
    // ---- S^T = K Q^T, split accumulators (chain depth 4) ----
    f32x4 sva[4] = {}, svb[4] = {};
    PRIO1();
#pragma unroll
    for (int kb = 0; kb < 4; kb++) {
      const char* krow = (const char*)&lK[buf][(kb * 16 + l15) * 256];
      const int sw = ((kb * 16 + l15) & 7) << 4;
#pragma unroll
      for (int kc = 0; kc < 4; kc++) {
        bf16x8 kfa = *(const bf16x8*)(krow + ((kc * 64 + l4 * 16) ^ sw));
        bf16x8 kfb = *(const bf16x8*)(krow + (((kc + 4) * 64 + l4 * 16) ^ sw));
        sva[kb] = __builtin_amdgcn_mfma_f32_16x16x32_bf16(kfa, qfr[kc], sva[kb], 0, 0, 0);
        svb[kb] = __builtin_amdgcn_mfma_f32_16x16x32_bf16(kfb, qfr[kc + 4], svb[kb], 0, 0, 0);
      }
    }
    PRIO0();
    // ---- mask (index math) + local max over 16 + cross-group reduce ----
    float p[4][4];
    float pmax = -__builtin_inff();
#pragma unroll
    for (int kb = 0; kb < 4; kb++)
#pragma unroll
      for (int r = 0; r < 4; r++) {
        int key = t0 + kb * 16 + l4 * 4 + r;
        bool ok = (key <= qpos) && (qpos - key < WIN);
        p[kb][r] = ok ? (sva[kb][r] + svb[kb][r]) : -__builtin_inff();
        pmax = fmaxf(pmax, p[kb][r]);
      }
    pmax = fmaxf(pmax, __shfl_xor(pmax, 16));
    pmax = fmaxf(pmax, __shfl_xor(pmax, 32));
    // ---- defer-max rescale (THR=8) ----
    bool resc = __any(pmax - mreg > 8.0f);
    if (resc) {
      float nm = fmaxf(mreg, pmax);
      float al = __expf(mreg - nm);
      mreg = nm;
      lreg *= al;
      float alr[4];
#pragma unroll
      for (int r = 0; r < 4; r++) alr[r] = __shfl(al, l4 * 4 + r);
#pragma unroll
      for (int nd = 0; nd < 16; nd++)
#pragma unroll
        for (int r = 0; r < 4; r++) acc[nd][r] *= alr[r];
    }
    // ---- exp + sum ----
    float sum = 0.0f;
#pragma unroll
    for (int kb = 0; kb < 4; kb++)
#pragma unroll
      for (int r = 0; r < 4; r++) {
        p[kb][r] = __expf(p[kb][r] - mreg);
        sum += p[kb][r];
      }
    sum += __shfl_xor(sum, 16);
    sum += __shfl_xor(sum, 32);
    lreg += sum;
    // ---- pack P to bf16 pairs ----
    uint32_t pk[4][2];
#pragma unroll
    for (int kb = 0; kb < 4; kb++)
#pragma unroll
      for (int h = 0; h < 2; h++)
        pk[kb][h] = (uint32_t)f2bf(p[kb][2 * h]) |
                    ((uint32_t)f2bf(p[kb][2 * h + 1]) << 16);
    // ---- gather BOTH PV A-frags upfront (bpermute latencies overlap) ----
    const int srcA = 32 * (l4 & 1) + l15;
    const bool lo = lane < 32;
    bf16x8 paH[2];
#pragma unroll
    for (int H = 0; H < 2; H++) {
      uint32_t fr[4];
      uint32_t a0 = __shfl(pk[2 * H][0], srcA), b0 = __shfl(pk[2 * H + 1][0], srcA);
      uint32_t a1 = __shfl(pk[2 * H][1], srcA), b1 = __shfl(pk[2 * H + 1][1], srcA);
      uint32_t a2 = __shfl(pk[2 * H][0], srcA + 16), b2 = __shfl(pk[2 * H + 1][0], srcA + 16);
      uint32_t a3 = __shfl(pk[2 * H][1], srcA + 16), b3 = __shfl(pk[2 * H + 1][1], srcA + 16);
      fr[0] = lo ? a0 : b0;
      fr[1] = lo ? a1 : b1;
      fr[2] = lo ? a2 : b2;
      fr[3] = lo ? a3 : b3;
      memcpy(&paH[H], fr, 16);
    }
    // ---- PV: 32 MFMAs in one priority region ----
    PRIO1();
#pragma unroll
    for (int H = 0; H < 2; H++)
#pragma unroll
      for (int nd = 0; nd < 16; nd++) {
        int d = nd * 16 + l15;
        bf16x8 vf = *(const bf16x8*)((const char*)&lV[buf][d * 64] +
                                     ((H * 64 + l4 * 16) ^ ((d & 7) << 4)));
        acc[nd] = __builtin_amdgcn_mfma_f32_16x16x32_bf16(paH[H], vf, acc[nd], 0, 0, 0);
      }
    PRIO0();
    __syncthreads();  // next-tile stage landed + all reads of buf done
    buf ^= 1;
  }
  // final 1/l, transposed from q=l15 indexing to q=l4*4+r (output C-layout rows)
  float rinv = 1.0f / lreg;
  float rv[4];
#pragma unroll
  for (int r = 0; r < 4; r++) rv[r] = __shfl(rinv, l4 * 4 + r);
#pragma unroll
  for (int nd = 0; nd < 16; nd++)
#pragma unroll
    for (int r = 0; r < 4; r++) {
      size_t row = qw + l4 * 4 + r;
      aout[row * AO_N + head * HD + nd * 16 + l15] = f2bf(acc[nd][r] * rv[r]);
    }
#undef STAGE_KV
}

extern "C" void kernel_launch(void* const* d_in, const int* in_sizes, int n_in,
                              void* d_out, int out_size, void* d_ws, size_t ws_size,
                              hipStream_t stream) {
  const float* x = (const float*)d_in[0];
  const int* pos = (const int*)d_in[1];
  const float* wq = (const float*)d_in[2];
  const float* wk = (const float*)d_in[3];
  const float* wv = (const float*)d_in[4];
  const float* wo = (const float*)d_in[5];
  const float* qnw = (const float*)d_in[6];
  const float* knw = (const float*)d_in[7];

  // scratch layout:
  //   d_out [0,33.5MB): qkv bf16 [4096][4096]; [33.5,35.6): ctab; [35.6,37.7): stab
  //   ws+0        : x bf16 [4096][2304]; later aout bf16 [4096][2048]
  //   ws+18874368 : W^T bf16 (qkv-phase: [4096][2304]; out-phase: wo^T [2304][2048])
  //   ws+28311552 : vt bf16 [4][256][4096] (written by gemm<1> V-epilogue)
  u16* qkv = (u16*)d_out;
  float* ctab = (float*)((char*)d_out + 33554432);
  float* stab = (float*)((char*)d_out + 35651584);
  u16* xbf = (u16*)d_ws;
  u16* wT = (u16*)((char*)d_ws + 18874368);
  u16* vtb = (u16*)((char*)d_ws + 28311552);
  u16* aout = xbf;

  k_prep<<<20480, 256, 0, stream>>>(x, xbf, pos, ctab, stab, wq, wk, wv, wT);
  k_gemm8p<1><<<dim3(256), 512, 0, stream>>>(xbf, wT, qkv, S_LEN, QKV_N, HID_DIM,
                                             ctab, stab, qnw, knw, vtb);
  k_attn<<<dim3(4864), 512, 0, stream>>>(qkv, vtb, pos, aout, wo, wT);
  k_gemm192<<<dim3(192), 512, 0, stream>>>(aout, wT, (float*)d_out, S_LEN, HID_DIM, 2048);
}

// Round 23
// 219.535 us; speedup vs baseline: 1.0207x; 1.0207x over previous
//
#include <hip/hip_runtime.h>
#include <stdint.h>

typedef unsigned short u16;
typedef __attribute__((ext_vector_type(8))) short bf16x8;
typedef __attribute__((ext_vector_type(4))) float f32x4;

#define S_LEN 4096
#define HID_DIM 2304
#define QKV_N 4096
#define AO_N 2048
#define HD 256
#define WIN 1024
#define QSCALE 0.0625f

static __device__ __forceinline__ u16 f2bf(float f) {
  union { float f; uint32_t u; } v; v.f = f;
  return (u16)((v.u + 0x7FFFu + ((v.u >> 16) & 1u)) >> 16);
}
static __device__ __forceinline__ float bf2f(u16 h) {
  union { uint32_t u; float f; } v; v.u = ((uint32_t)h) << 16;
  return v.f;
}

static __device__ __forceinline__ void gld16(const void* src, void* dst) {
  __builtin_amdgcn_global_load_lds((const __attribute__((address_space(1))) void*)src,
                                   (__attribute__((address_space(3))) void*)dst, 16, 0, 0);
}

#define BAR() __builtin_amdgcn_s_barrier()
#define LG0() asm volatile("s_waitcnt lgkmcnt(0)" ::: "memory")
#define VM6() asm volatile("s_waitcnt vmcnt(6)" ::: "memory")
#define VM5() asm volatile("s_waitcnt vmcnt(5)" ::: "memory")
#define VM4() asm volatile("s_waitcnt vmcnt(4)" ::: "memory")
#define VM3() asm volatile("s_waitcnt vmcnt(3)" ::: "memory")
#define VM2() asm volatile("s_waitcnt vmcnt(2)" ::: "memory")
#define VM0() asm volatile("s_waitcnt vmcnt(0)" ::: "memory")
#define PRIO1() __builtin_amdgcn_s_setprio(1)
#define PRIO0() __builtin_amdgcn_s_setprio(0)

// ---------------- fused prep: x->bf16 | RoPE tables | wq/wk/wv transpose ----------------
// blocks [0,9216): cvt x; [9216,11264): sincos; [11264,20480): transpose_w.
__global__ __launch_bounds__(256) void k_prep(const float* __restrict__ x,
                                              u16* __restrict__ xbf,
                                              const int* __restrict__ pos_ids,
                                              float* __restrict__ ctab,
                                              float* __restrict__ stab,
                                              const float* __restrict__ wq,
                                              const float* __restrict__ wk,
                                              const float* __restrict__ wv,
                                              u16* __restrict__ wT) {
  __shared__ float tile[32][33];
  const int b = blockIdx.x;
  if (b < 9216) {
    int i = (b * 256 + threadIdx.x) * 4;
    float4 v = *(const float4*)(x + i);
    uint64_t p = (uint64_t)f2bf(v.x) | ((uint64_t)f2bf(v.y) << 16)
               | ((uint64_t)f2bf(v.z) << 32) | ((uint64_t)f2bf(v.w) << 48);
    *(uint64_t*)(xbf + i) = p;
  } else if (b < 11264) {
    int idx = (b - 9216) * 256 + threadIdx.x;  // 4096*128
    int s = idx >> 7, j = idx & 127;
    float ang = (float)pos_ids[s] * exp2f((float)j * (-13.287712379549449f / 128.0f));
    float sn, c;
    sincosf(ang, &sn, &c);
    ctab[idx] = c;
    stab[idx] = sn;
  } else {
    int bb = b - 11264;           // 0..9215
    int ct = bb & 127;            // 0..127 -> out rows ct*32..+31
    int r0 = (bb >> 7) * 32;      // over 2304
    const float* src;
    int C, c0;
    if (ct < 64) {
      src = wq; C = 2048; c0 = ct * 32;
    } else if (ct < 96) {
      src = wk; C = 1024; c0 = (ct - 64) * 32;
    } else {
      src = wv; C = 1024; c0 = (ct - 96) * 32;
    }
    int tx = threadIdx.x & 31, ty = threadIdx.x >> 5;
#pragma unroll
    for (int i = 0; i < 4; i++)
      tile[ty + i * 8][tx] = src[(size_t)(r0 + ty + i * 8) * C + c0 + tx];
    __syncthreads();
#pragma unroll
    for (int i = 0; i < 4; i++)
      wT[(size_t)(ct * 32 + ty + i * 8) * HID_DIM + r0 + tx] = f2bf(tile[tx][ty + i * 8]);
  }
}

// in: fp32 [R][C] row-major; out bf16: out[(row_off + c)*out_stride + r] = in[r][c]
__global__ __launch_bounds__(256) void k_transpose_cvt(const float* __restrict__ in, int C,
                                                       u16* __restrict__ out, int out_stride,
                                                       int row_off) {
  __shared__ float tile[32][33];
  int c0 = blockIdx.x * 32, r0 = blockIdx.y * 32;
  int tx = threadIdx.x & 31, ty = threadIdx.x >> 5;
#pragma unroll
  for (int i = 0; i < 4; i++)
    tile[ty + i * 8][tx] = in[(size_t)(r0 + ty + i * 8) * C + c0 + tx];
  __syncthreads();
#pragma unroll
  for (int i = 0; i < 4; i++)
    out[(size_t)(row_off + c0 + ty + i * 8) * out_stride + r0 + tx] = f2bf(tile[tx][ty + i * 8]);
}

// ---------------- bf16 GEMM: 256x256, BK=64, 4-phase, uniform lag-4 staging -------------
// (R16-proven.) MODE 1 fused epilogue (2-m slab rounds; coalesced V stores). 2D XCD rect.
template <int MODE>
__global__ __launch_bounds__(512, 2) void k_gemm8p(const u16* __restrict__ A,
                                                   const u16* __restrict__ Bt,
                                                   void* __restrict__ Cout,
                                                   int M, int N, int K,
                                                   const float* __restrict__ ctab,
                                                   const float* __restrict__ stab,
                                                   const float* __restrict__ qnw,
                                                   const float* __restrict__ knw,
                                                   u16* __restrict__ vtb) {
  __shared__ u16 sAB[4 * 256 * 64];  // sA0, sA1, sB0, sB1 (contiguous)
  const int t = threadIdx.x, lane = t & 63, wave = t >> 6;
  const int wr = wave >> 2, wc = wave & 3;
  const int l15 = lane & 15, l4 = lane >> 4;
  const int nbn = N >> 8;
  int bm, bn;
  {
    const int xcd = (int)blockIdx.x & 7, loc = (int)blockIdx.x >> 3;
    if (nbn == 16) {  // grid 256: 4bm x 8bn rect per XCD
      bm = (xcd >> 1) * 4 + (loc >> 3);
      bn = (xcd & 1) * 8 + (loc & 7);
    } else {
      const int cpx = gridDim.x >> 3;
      const int wg = xcd * cpx + loc;
      bm = wg / nbn;
      bn = wg % nbn;
    }
  }
  const int NT = K >> 6;
  const int srow = lane >> 3;
  const int sslot = ((lane & 7) ^ srow) * 8;
  const u16* Abase = A + (size_t)(bm * 256) * K;
  const u16* Bbase = Bt + (size_t)(bn * 256) * K;
  f32x4 acc[8][4] = {};
  bf16x8 aF[4][2], b01[2][2], b23[2][2];

#define SA_(b) (&sAB[(b) * 16384])
#define SB_(b) (&sAB[32768 + (b) * 16384])
#define STG_A(BUF, HALF, KT) do {                                                 \
    _Pragma("unroll")                                                             \
    for (int c_ = 0; c_ < 2; c_++) {                                              \
      int rb_ = (HALF) * 128 + (wave * 2 + c_) * 8;                               \
      gld16(Abase + (size_t)(rb_ + srow) * K + ((KT) << 6) + sslot,               \
            SA_(BUF) + rb_ * 64);                                                 \
    }                                                                             \
  } while (0)
#define STG_B(BUF, HALF, KT) do {                                                 \
    _Pragma("unroll")                                                             \
    for (int c_ = 0; c_ < 2; c_++) {                                              \
      int rb_ = (HALF) * 128 + (wave * 2 + c_) * 8;                               \
      gld16(Bbase + (size_t)(rb_ + srow) * K + ((KT) << 6) + sslot,               \
            SB_(BUF) + rb_ * 64);                                                 \
    }                                                                             \
  } while (0)
#define LDA(BUF, M_, KK)                                                          \
  (*(const bf16x8*)&SA_(BUF)[((M_) * 32 + wr * 16 + l15) * 64 +                   \
                             ((((KK) << 2) + l4) ^ (l15 & 7)) * 8])
#define LDB(BUF, N_, KK)                                                          \
  (*(const bf16x8*)&SB_(BUF)[((N_) * 64 + wc * 16 + l15) * 64 +                   \
                             ((((KK) << 2) + l4) ^ (l15 & 7)) * 8])

#define P1_LOADS(b_) do {                                                         \
    _Pragma("unroll") for (int m_ = 0; m_ < 4; m_++)                              \
      _Pragma("unroll") for (int k_ = 0; k_ < 2; k_++)                            \
        aF[m_][k_] = LDA(b_, m_, k_);                                             \
    _Pragma("unroll") for (int n_ = 0; n_ < 2; n_++)                              \
      _Pragma("unroll") for (int k_ = 0; k_ < 2; k_++)                            \
        b01[n_][k_] = LDB(b_, n_, k_);                                            \
  } while (0)
#define P2_LOADS(b_) do {                                                         \
    _Pragma("unroll") for (int n_ = 0; n_ < 2; n_++)                              \
      _Pragma("unroll") for (int k_ = 0; k_ < 2; k_++)                            \
        b23[n_][k_] = LDB(b_, n_ + 2, k_);                                        \
  } while (0)
#define P3_LOADS(b_) do {                                                         \
    _Pragma("unroll") for (int m_ = 0; m_ < 4; m_++)                              \
      _Pragma("unroll") for (int k_ = 0; k_ < 2; k_++)                            \
        aF[m_][k_] = LDA(b_, m_ + 4, k_);                                         \
  } while (0)
#define MFMA16(MOFF, NOFF, BREG) do {                                             \
    _Pragma("unroll") for (int m_ = 0; m_ < 4; m_++)                              \
      _Pragma("unroll") for (int n_ = 0; n_ < 2; n_++)                            \
        _Pragma("unroll") for (int k_ = 0; k_ < 2; k_++)                          \
          acc[m_ + MOFF][n_ + NOFF] = __builtin_amdgcn_mfma_f32_16x16x32_bf16(    \
              aF[m_][k_], BREG[n_][k_], acc[m_ + MOFF][n_ + NOFF], 0, 0, 0);      \
  } while (0)

  STG_A(0, 0, 0);
  STG_B(0, 0, 0);
  STG_B(0, 1, 0);
  STG_A(0, 1, 0);
  VM4();
  BAR();

  for (int tt = 0; tt < NT - 1; ++tt) {
    const int b = tt & 1, nb = b ^ 1;
    P1_LOADS(b);
    STG_A(nb, 0, tt + 1);
    STG_B(nb, 0, tt + 1);
    BAR(); LG0(); PRIO1(); MFMA16(0, 0, b01); PRIO0();
    VM6();
    BAR();
    P2_LOADS(b);
    STG_B(nb, 1, tt + 1);
    BAR(); LG0(); PRIO1(); MFMA16(0, 2, b23); PRIO0();
    VM6();
    BAR();
    P3_LOADS(b);
    STG_A(nb, 1, tt + 1);
    BAR(); LG0(); PRIO1(); MFMA16(4, 0, b01); PRIO0();
    BAR();
    PRIO1(); MFMA16(4, 2, b23); PRIO0();
    VM4();
    BAR();
  }
  {
    const int b = (NT - 1) & 1;
    P1_LOADS(b);
    BAR(); LG0(); PRIO1(); MFMA16(0, 0, b01); PRIO0();
    VM2();
    BAR();
    P2_LOADS(b);
    BAR(); LG0(); PRIO1(); MFMA16(0, 2, b23); PRIO0();
    VM0();
    BAR();
    P3_LOADS(b);
    BAR(); LG0(); PRIO1(); MFMA16(4, 0, b01); PRIO0();
    BAR();
    PRIO1(); MFMA16(4, 2, b23); PRIO0();
  }

  if (MODE == 1) {
    __syncthreads();
    float* slab = (float*)sAB;  // [64][264] f32 (2 m-chunks per round)
    if (bn < 12) {
      const float* wvec = (bn < 8) ? qnw : knw;
      const float scl = (bn < 8) ? QSCALE : 1.0f;
      f32x4 wv4 = *(const f32x4*)&wvec[lane * 4];
#pragma unroll
      for (int mp = 0; mp < 4; mp++) {
#pragma unroll
        for (int mh = 0; mh < 2; mh++) {
          int m = mp * 2 + mh;
#pragma unroll
          for (int n = 0; n < 4; n++)
#pragma unroll
            for (int r = 0; r < 4; r++)
              slab[(mh * 32 + wr * 16 + l4 * 4 + r) * 264 + n * 64 + wc * 16 + l15] =
                  acc[m][n][r];
        }
        __syncthreads();
#pragma unroll
        for (int rr = 0; rr < 8; rr++) {
          int lrow = wave * 8 + rr;
          int grow = bm * 256 + mp * 64 + lrow;
          f32x4 v = *(const f32x4*)&slab[lrow * 264 + lane * 4];
          float ss = v[0] * v[0] + v[1] * v[1] + v[2] * v[2] + v[3] * v[3];
#pragma unroll
          for (int off = 1; off < 64; off <<= 1) ss += __shfl_xor(ss, off);
          float rms = rsqrtf(ss * (1.0f / 256.0f) + 1e-6f);
          float y[4], yo[4];
#pragma unroll
          for (int j = 0; j < 4; j++) y[j] = v[j] * rms * (1.0f + wv4[j]);
#pragma unroll
          for (int j = 0; j < 4; j++) yo[j] = __shfl_xor(y[j], 32);
          f32x4 cv = *(const f32x4*)&ctab[grow * 128 + (lane & 31) * 4];
          f32x4 sv = *(const f32x4*)&stab[grow * 128 + (lane & 31) * 4];
          uint64_t pk = 0;
#pragma unroll
          for (int j = 0; j < 4; j++) {
            float o = (lane < 32) ? (y[j] * cv[j] - yo[j] * sv[j])
                                  : (yo[j] * sv[j] + y[j] * cv[j]);
            pk |= (uint64_t)f2bf(o * scl) << (16 * j);
          }
          *(uint64_t*)&((u16*)Cout)[(size_t)grow * N + bn * 256 + lane * 4] = pk;
        }
        __syncthreads();
      }
    } else {
      const int kvh = bn - 12;
      const int dcol = wave * 32 + (lane >> 1);  // 0..255
      const int shalf = (lane & 1) * 32;
#pragma unroll
      for (int mp = 0; mp < 4; mp++) {
#pragma unroll
        for (int mh = 0; mh < 2; mh++) {
          int m = mp * 2 + mh;
#pragma unroll
          for (int n = 0; n < 4; n++)
#pragma unroll
            for (int r = 0; r < 4; r++)
              slab[(mh * 32 + wr * 16 + l4 * 4 + r) * 264 + n * 64 + wc * 16 + l15] =
                  acc[m][n][r];
        }
        __syncthreads();
        u16* dst = vtb + (size_t)(kvh * 256 + dcol) * S_LEN + bm * 256 + mp * 64 + shalf;
#pragma unroll
        for (int g = 0; g < 4; g++) {
          u16 tmp[8];
#pragma unroll
          for (int jj = 0; jj < 8; jj++)
            tmp[jj] = f2bf(slab[(shalf + g * 8 + jj) * 264 + dcol]);
          *(bf16x8*)(dst + g * 8) = *(const bf16x8*)tmp;
        }
        __syncthreads();
      }
    }
  } else {
#pragma unroll
    for (int m = 0; m < 8; m++)
#pragma unroll
      for (int n = 0; n < 4; n++)
#pragma unroll
        for (int r = 0; r < 4; r++) {
          size_t row = bm * 256 + m * 32 + wr * 16 + l4 * 4 + r;
          size_t col = bn * 256 + n * 64 + wc * 16 + l15;
          ((float*)Cout)[row * N + col] = acc[m][n][r];
        }
  }
#undef SA_
#undef SB_
#undef STG_A
#undef STG_B
#undef LDA
#undef LDB
#undef P1_LOADS
#undef P2_LOADS
#undef P3_LOADS
#undef MFMA16
}

// ---------------- bf16 GEMM 256x192 (out-proj): 4-phase, uniform lag-4 staging ----------
__global__ __launch_bounds__(512, 2) void k_gemm192(const u16* __restrict__ A,
                                                    const u16* __restrict__ Bt,
                                                    float* __restrict__ Cout,
                                                    int M, int N, int K) {
  __shared__ u16 sA[2][256 * 64];
  __shared__ u16 sB[2][192 * 64];
  const int t = threadIdx.x, lane = t & 63, wave = t >> 6;
  const int wr = wave >> 2, wc = wave & 3;
  const int l15 = lane & 15, l4 = lane >> 4;
  const int xcd = (int)blockIdx.x & 7, loc = (int)blockIdx.x >> 3;  // loc 0..23
  const int bm = (xcd >> 1) * 4 + loc / 6;
  const int bn = (xcd & 1) * 6 + loc % 6;
  const int NT = K >> 6;
  const int srow = lane >> 3;
  const int sslot = ((lane & 7) ^ srow) * 8;
  const u16* Abase = A + (size_t)(bm * 256) * K;
  const u16* Bbase = Bt + (size_t)(bn * 192) * K;
  f32x4 acc[8][3] = {};
  bf16x8 aF[4][2], b01[2][2], b2[2];

#define GA_STG_A(BUF, HALF, KT) do {                                              \
    _Pragma("unroll")                                                             \
    for (int c_ = 0; c_ < 2; c_++) {                                              \
      int rb_ = (HALF) * 128 + (wave * 2 + c_) * 8;                               \
      gld16(Abase + (size_t)(rb_ + srow) * K + ((KT) << 6) + sslot,               \
            &sA[BUF][rb_ * 64]);                                                  \
    }                                                                             \
  } while (0)
#define GA_STG_BC(BUF, CH, KT) do {                                               \
    int rb_ = (CH) * 64 + wave * 8;                                               \
    gld16(Bbase + (size_t)(rb_ + srow) * K + ((KT) << 6) + sslot,                 \
          &sB[BUF][rb_ * 64]);                                                    \
  } while (0)
#define GA_LDA(BUF, M_, KK)                                                       \
  (*(const bf16x8*)&sA[BUF][((M_) * 32 + wr * 16 + l15) * 64 +                    \
                            ((((KK) << 2) + l4) ^ (l15 & 7)) * 8])
#define GA_LDB(BUF, N_, KK)                                                       \
  (*(const bf16x8*)&sB[BUF][((N_) * 64 + wc * 16 + l15) * 64 +                    \
                            ((((KK) << 2) + l4) ^ (l15 & 7)) * 8])
#define GA_P1_LOADS(b_) do {                                                      \
    _Pragma("unroll") for (int m_ = 0; m_ < 4; m_++)                              \
      _Pragma("unroll") for (int k_ = 0; k_ < 2; k_++)                            \
        aF[m_][k_] = GA_LDA(b_, m_, k_);                                          \
    _Pragma("unroll") for (int n_ = 0; n_ < 2; n_++)                              \
      _Pragma("unroll") for (int k_ = 0; k_ < 2; k_++)                            \
        b01[n_][k_] = GA_LDB(b_, n_, k_);                                         \
  } while (0)
#define GA_P2_LOADS(b_) do {                                                      \
    _Pragma("unroll") for (int k_ = 0; k_ < 2; k_++)                              \
      b2[k_] = GA_LDB(b_, 2, k_);                                                 \
  } while (0)
#define GA_P3_LOADS(b_) do {                                                      \
    _Pragma("unroll") for (int m_ = 0; m_ < 4; m_++)                              \
      _Pragma("unroll") for (int k_ = 0; k_ < 2; k_++)                            \
        aF[m_][k_] = GA_LDA(b_, m_ + 4, k_);                                      \
  } while (0)
#define GA_MFMA_N01(MOFF) do {                                                    \
    _Pragma("unroll") for (int m_ = 0; m_ < 4; m_++)                              \
      _Pragma("unroll") for (int n_ = 0; n_ < 2; n_++)                            \
        _Pragma("unroll") for (int k_ = 0; k_ < 2; k_++)                          \
          acc[m_ + MOFF][n_] = __builtin_amdgcn_mfma_f32_16x16x32_bf16(           \
              aF[m_][k_], b01[n_][k_], acc[m_ + MOFF][n_], 0, 0, 0);              \
  } while (0)
#define GA_MFMA_N2(MOFF) do {                                                     \
    _Pragma("unroll") for (int m_ = 0; m_ < 4; m_++)                              \
      _Pragma("unroll") for (int k_ = 0; k_ < 2; k_++)                            \
        acc[m_ + MOFF][2] = __builtin_amdgcn_mfma_f32_16x16x32_bf16(              \
            aF[m_][k_], b2[k_], acc[m_ + MOFF][2], 0, 0, 0);                      \
  } while (0)

  GA_STG_A(0, 0, 0);
  GA_STG_BC(0, 0, 0);
  GA_STG_BC(0, 1, 0);
  GA_STG_BC(0, 2, 0);
  GA_STG_A(0, 1, 0);
  VM3();
  BAR();

  for (int tt = 0; tt < NT - 1; ++tt) {
    const int b = tt & 1, nb = b ^ 1;
    GA_P1_LOADS(b);
    GA_STG_A(nb, 0, tt + 1);
    GA_STG_BC(nb, 0, tt + 1);
    GA_STG_BC(nb, 1, tt + 1);
    BAR(); LG0(); PRIO1(); GA_MFMA_N01(0); PRIO0();
    VM6();
    BAR();
    GA_P2_LOADS(b);
    GA_STG_BC(nb, 2, tt + 1);
    BAR(); LG0(); PRIO1(); GA_MFMA_N2(0); PRIO0();
    VM5();
    BAR();
    GA_P3_LOADS(b);
    GA_STG_A(nb, 1, tt + 1);
    BAR(); LG0(); PRIO1(); GA_MFMA_N01(4); PRIO0();
    BAR();
    PRIO1(); GA_MFMA_N2(4); PRIO0();
    VM3();
    BAR();
  }
  {
    const int b = (NT - 1) & 1;
    GA_P1_LOADS(b);
    BAR(); LG0(); PRIO1(); GA_MFMA_N01(0); PRIO0();
    VM2();
    BAR();
    GA_P2_LOADS(b);
    BAR(); LG0(); PRIO1(); GA_MFMA_N2(0); PRIO0();
    VM0();
    BAR();
    GA_P3_LOADS(b);
    BAR(); LG0(); PRIO1(); GA_MFMA_N01(4); PRIO0();
    BAR();
    PRIO1(); GA_MFMA_N2(4); PRIO0();
  }

#pragma unroll
  for (int m = 0; m < 8; m++)
#pragma unroll
    for (int n = 0; n < 3; n++)
#pragma unroll
      for (int r = 0; r < 4; r++) {
        size_t row = bm * 256 + m * 32 + wr * 16 + l4 * 4 + r;
        size_t col = bn * 192 + n * 64 + wc * 16 + l15;
        Cout[row * N + col] = acc[m][n][r];
      }
#undef GA_STG_A
#undef GA_STG_BC
#undef GA_LDA
#undef GA_LDB
#undef GA_P1_LOADS
#undef GA_P2_LOADS
#undef GA_P3_LOADS
#undef GA_MFMA_N01
#undef GA_MFMA_N2
}

// ---------------- flash attention v10: swapped-QK in-reg softmax + ILP tuning ----------
__global__ __launch_bounds__(512, 2) void k_attn(const u16* __restrict__ qkv,
                                                 const u16* __restrict__ vt,
                                                 const int* __restrict__ pos_ids,
                                                 u16* __restrict__ aout) {
  __shared__ u16 lK[2][64 * 256];  // [key][d], rows 512B, swizzled
  __shared__ u16 lV[2][256 * 64];  // [d][key], rows 128B, swizzled
  const int bid = blockIdx.x;      // 256 blocks
  const int wg = (bid & 7) * 32 + (bid >> 3);  // bijective XCD swizzle
  const int kvh = wg >> 6;                     // 0..3
  const int q0 = (wg & 63) * 64;               // 0..4032
  const int t = threadIdx.x, lane = t & 63, wave = t >> 6;
  const int l15 = lane & 15, l4 = lane >> 4;
  const int head = kvh * 2 + (wave >> 2);
  const int qw = q0 + (wave & 3) * 16;

  bf16x8 qfr[8];
  {
    const u16* qptr = qkv + (size_t)(qw + l15) * QKV_N + head * HD + l4 * 8;
#pragma unroll
    for (int kc = 0; kc < 8; kc++) qfr[kc] = *(const bf16x8*)(qptr + kc * 32);
  }
  f32x4 acc[16] = {};
  float mreg = -1e30f, lreg = 0.0f;        // per-lane, query q = qw + l15
  const int qpos = qw + l15;               // pos_ids is arange (per problem setup)

  const int krw = lane >> 5, kcl = lane & 31;
  const int vrw = lane >> 3, vcl = lane & 7;
  const u16* kgb = qkv + 2048 + kvh * HD;
  const u16* vgb = vt + (size_t)kvh * HD * S_LEN;

  int start = q0 - (WIN - 1);
  if (start < 0) start = 0;
  start &= ~63;

#define STAGE_KV(B, T0) do {                                                          \
    _Pragma("unroll")                                                                 \
    for (int i_ = 0; i_ < 4; i_++) {                                                  \
      int ch_ = wave * 4 + i_;                                                        \
      int kr_ = ch_ * 2 + krw;                                                        \
      gld16(kgb + (size_t)((T0) + kr_) * QKV_N + ((kcl ^ (kr_ & 7)) * 8),             \
            &lK[B][ch_ * 512]);                                                       \
      int vr_ = ch_ * 8 + vrw;                                                        \
      gld16(vgb + (size_t)vr_ * S_LEN + (T0) + ((vcl ^ (vr_ & 7)) * 8),               \
            &lV[B][ch_ * 512]);                                                       \
    }                                                                                 \
  } while (0)

  STAGE_KV(0, start);
  __syncthreads();
  int buf = 0;
  for (int t0 = start; t0 <= q0 + 63; t0 += 64) {
    if (t0 + 64 <= q0 + 63) STAGE_KV(buf ^ 1, t0 + 64);
    // ---- S^T = K Q^T, split accumulators (chain depth 4) ----
    f32x4 sva[4] = {}, svb[4] = {};
    PRIO1();
#pragma unroll
    for (int kb = 0; kb < 4; kb++) {
      const char* krow = (const char*)&lK[buf][(kb * 16 + l15) * 256];
      const int sw = ((kb * 16 + l15) & 7) << 4;
#pragma unroll
      for (int kc = 0; kc < 4; kc++) {
        bf16x8 kfa = *(const bf16x8*)(krow + ((kc * 64 + l4 * 16) ^ sw));
        bf16x8 kfb = *(const bf16x8*)(krow + (((kc + 4) * 64 + l4 * 16) ^ sw));
        sva[kb] = __builtin_amdgcn_mfma_f32_16x16x32_bf16(kfa, qfr[kc], sva[kb], 0, 0, 0);
        svb[kb] = __builtin_amdgcn_mfma_f32_16x16x32_bf16(kfb, qfr[kc + 4], svb[kb], 0, 0, 0);
      }
    }
    PRIO0();
    // ---- mask (index math) + local max over 16 + cross-group reduce ----
    float p[4][4];
    float pmax = -__builtin_inff();
#pragma unroll
    for (int kb = 0; kb < 4; kb++)
#pragma unroll
      for (int r = 0; r < 4; r++) {
        int key = t0 + kb * 16 + l4 * 4 + r;
        bool ok = (key <= qpos) && (qpos - key < WIN);
        p[kb][r] = ok ? (sva[kb][r] + svb[kb][r]) : -__builtin_inff();
        pmax = fmaxf(pmax, p[kb][r]);
      }
    pmax = fmaxf(pmax, __shfl_xor(pmax, 16));
    pmax = fmaxf(pmax, __shfl_xor(pmax, 32));
    // ---- defer-max rescale (THR=8) ----
    bool resc = __any(pmax - mreg > 8.0f);
    if (resc) {
      float nm = fmaxf(mreg, pmax);
      float al = __expf(mreg - nm);
      mreg = nm;
      lreg *= al;
      float alr[4];
#pragma unroll
      for (int r = 0; r < 4; r++) alr[r] = __shfl(al, l4 * 4 + r);
#pragma unroll
      for (int nd = 0; nd < 16; nd++)
#pragma unroll
        for (int r = 0; r < 4; r++) acc[nd][r] *= alr[r];
    }
    // ---- exp + sum ----
    float sum = 0.0f;
#pragma unroll
    for (int kb = 0; kb < 4; kb++)
#pragma unroll
      for (int r = 0; r < 4; r++) {
        p[kb][r] = __expf(p[kb][r] - mreg);
        sum += p[kb][r];
      }
    sum += __shfl_xor(sum, 16);
    sum += __shfl_xor(sum, 32);
    lreg += sum;
    // ---- pack P to bf16 pairs ----
    uint32_t pk[4][2];
#pragma unroll
    for (int kb = 0; kb < 4; kb++)
#pragma unroll
      for (int h = 0; h < 2; h++)
        pk[kb][h] = (uint32_t)f2bf(p[kb][2 * h]) |
                    ((uint32_t)f2bf(p[kb][2 * h + 1]) << 16);
    // ---- gather BOTH PV A-frags upfront (bpermute latencies overlap) ----
    const int srcA = 32 * (l4 & 1) + l15;
    const bool lo = lane < 32;
    bf16x8 paH[2];
#pragma unroll
    for (int H = 0; H < 2; H++) {
      uint32_t fr[4];
      uint32_t a0 = __shfl(pk[2 * H][0], srcA), b0 = __shfl(pk[2 * H + 1][0], srcA);
      uint32_t a1 = __shfl(pk[2 * H][1], srcA), b1 = __shfl(pk[2 * H + 1][1], srcA);
      uint32_t a2 = __shfl(pk[2 * H][0], srcA + 16), b2 = __shfl(pk[2 * H + 1][0], srcA + 16);
      uint32_t a3 = __shfl(pk[2 * H][1], srcA + 16), b3 = __shfl(pk[2 * H + 1][1], srcA + 16);
      fr[0] = lo ? a0 : b0;
      fr[1] = lo ? a1 : b1;
      fr[2] = lo ? a2 : b2;
      fr[3] = lo ? a3 : b3;
      memcpy(&paH[H], fr, 16);
    }
    // ---- PV: 32 MFMAs in one priority region ----
    PRIO1();
#pragma unroll
    for (int H = 0; H < 2; H++)
#pragma unroll
      for (int nd = 0; nd < 16; nd++) {
        int d = nd * 16 + l15;
        bf16x8 vf = *(const bf16x8*)((const char*)&lV[buf][d * 64] +
                                     ((H * 64 + l4 * 16) ^ ((d & 7) << 4)));
        acc[nd] = __builtin_amdgcn_mfma_f32_16x16x32_bf16(paH[H], vf, acc[nd], 0, 0, 0);
      }
    PRIO0();
    __syncthreads();  // next-tile stage landed + all reads of buf done
    buf ^= 1;
  }
  // final 1/l, transposed from q=l15 indexing to q=l4*4+r (output C-layout rows)
  float rinv = 1.0f / lreg;
  float rv[4];
#pragma unroll
  for (int r = 0; r < 4; r++) rv[r] = __shfl(rinv, l4 * 4 + r);
#pragma unroll
  for (int nd = 0; nd < 16; nd++)
#pragma unroll
    for (int r = 0; r < 4; r++) {
      size_t row = qw + l4 * 4 + r;
      aout[row * AO_N + head * HD + nd * 16 + l15] = f2bf(acc[nd][r] * rv[r]);
    }
#undef STAGE_KV
}

extern "C" void kernel_launch(void* const* d_in, const int* in_sizes, int n_in,
                              void* d_out, int out_size, void* d_ws, size_t ws_size,
                              hipStream_t stream) {
  const float* x = (const float*)d_in[0];
  const int* pos = (const int*)d_in[1];
  const float* wq = (const float*)d_in[2];
  const float* wk = (const float*)d_in[3];
  const float* wv = (const float*)d_in[4];
  const float* wo = (const float*)d_in[5];
  const float* qnw = (const float*)d_in[6];
  const float* knw = (const float*)d_in[7];

  // scratch layout:
  //   d_out [0,33.5MB): qkv bf16 [4096][4096]; [33.5,35.6): ctab; [35.6,37.7): stab
  //   ws+0        : x bf16 [4096][2304]; later aout bf16 [4096][2048]
  //   ws+18874368 : W^T bf16 (qkv-phase: [4096][2304]; out-phase: wo^T [2304][2048])
  //   ws+28311552 : vt bf16 [4][256][4096] (written by gemm<1> V-epilogue)
  u16* qkv = (u16*)d_out;
  float* ctab = (float*)((char*)d_out + 33554432);
  float* stab = (float*)((char*)d_out + 35651584);
  u16* xbf = (u16*)d_ws;
  u16* wT = (u16*)((char*)d_ws + 18874368);
  u16* vtb = (u16*)((char*)d_ws + 28311552);
  u16* aout = xbf;

  k_prep<<<20480, 256, 0, stream>>>(x, xbf, pos, ctab, stab, wq, wk, wv, wT);
  k_gemm8p<1><<<dim3(256), 512, 0, stream>>>(xbf, wT, qkv, S_LEN, QKV_N, HID_DIM,
                                             ctab, stab, qnw, knw, vtb);
  k_transpose_cvt<<<dim3(72, 64), 256, 0, stream>>>(wo, HID_DIM, wT, 2048, 0);
  k_attn<<<dim3(256), 512, 0, stream>>>(qkv, vtb, pos, aout);
  k_gemm192<<<dim3(192), 512, 0, stream>>>(aout, wT, (float*)d_out, S_LEN, HID_DIM, 2048);
}